// Round 5
// baseline (387.097 us; speedup 1.0000x reference)
//
#include <hip/hip_runtime.h>
#include <hip/hip_bf16.h>

#define B_SZ   2
#define N_SEQ  2048
#define NH     16
#define DH     128
#define DM     2048
#define QB     128               // 4 warps x 32 q-rows
#define KVB    64
#define NQT    (N_SEQ / QB)      // 16
#define MASK_VAL (-50000.0f)

typedef short bf16x8 __attribute__((ext_vector_type(8)));
typedef float f32x4  __attribute__((ext_vector_type(4)));
typedef float f32x16 __attribute__((ext_vector_type(16)));
typedef unsigned u32;
typedef unsigned u32x2 __attribute__((ext_vector_type(2)));
typedef unsigned u32x4 __attribute__((ext_vector_type(4)));

__device__ __forceinline__ u32 pk2(float a, float b) {
  u32 r;
  asm("v_cvt_pk_bf16_f32 %0, %1, %2" : "=v"(r) : "v"(a), "v"(b));
  return r;
}

__global__ __launch_bounds__(256, 2)
void attn_fwd(const float* __restrict__ q, const float* __restrict__ k,
              const float* __restrict__ v, float* __restrict__ out) {
  __shared__ __align__(16) char  ldsK[2 * 64 * 256];    // dbuf K[64][128] bf16, swizzled
  __shared__ __align__(16) char  ldsVT[2 * 128 * 128];  // dbuf VT[128 d][64 j] bf16, swizzled
  __shared__ __align__(16) float ldsA[4 * 32];          // per-warp alpha/inv broadcast

  const int tid  = threadIdx.x;
  const int lane = tid & 63;
  const int w    = tid >> 6;
  const int h    = lane >> 5;     // wave half
  const int il   = lane & 31;

  const int bid = blockIdx.x;
  const int bh  = bid & 31;
  const int qt  = (bid < 256) ? (bid >> 5) : (NQT - 1 - ((bid - 256) >> 5));
  const int b   = bh >> 4;
  const int hd  = bh & 15;
  const int q0  = qt * QB;
  const int wq0 = q0 + w * 32;
  const int irow = wq0 + il;

  const float scale = 0.08838834764831845f;  // 128^-0.5

  const float* kb = k + (size_t)b * N_SEQ * DM + hd * DH;
  const float* vb = v + (size_t)b * N_SEQ * DM + hd * DH;

  // ---- staging registers (T14 async split)
  float4 kr[8];
  float  vr[32];
  const int d_ = tid & 127;
  const int jh = tid >> 7;

  auto issue_loads = [&](int jt) {
    const float* kt = kb + (size_t)jt * DM;
    #pragma unroll
    for (int i = 0; i < 8; ++i) {
      int idx = i * 256 + tid;
      int row = idx >> 5;
      int c4  = idx & 31;
      kr[i] = *(const float4*)(kt + (size_t)row * DM + c4 * 4);
    }
    const float* vt = vb + (size_t)jt * DM;
    #pragma unroll
    for (int t2 = 0; t2 < 4; ++t2) {
      int j0 = jh * 32 + t2 * 8;
      #pragma unroll
      for (int jj = 0; jj < 8; ++jj)
        vr[t2 * 8 + jj] = vt[(size_t)(j0 + jj) * DM + d_];
    }
  };

  auto write_lds = [&](int buf) {
    char* K  = ldsK  + buf * 16384;
    char* VT = ldsVT + buf * 16384;
    #pragma unroll
    for (int i = 0; i < 8; ++i) {
      int idx = i * 256 + tid;
      int row = idx >> 5;
      int c4  = idx & 31;
      u32x2 p;
      p[0] = pk2(kr[i].x, kr[i].y);
      p[1] = pk2(kr[i].z, kr[i].w);
      *(u32x2*)(K + row * 256 + ((c4 * 8) ^ ((row & 7) << 4))) = p;
    }
    #pragma unroll
    for (int t2 = 0; t2 < 4; ++t2) {
      int j0 = jh * 32 + t2 * 8;
      u32x4 p;
      p[0] = pk2(vr[t2 * 8 + 0], vr[t2 * 8 + 1]);
      p[1] = pk2(vr[t2 * 8 + 2], vr[t2 * 8 + 3]);
      p[2] = pk2(vr[t2 * 8 + 4], vr[t2 * 8 + 5]);
      p[3] = pk2(vr[t2 * 8 + 6], vr[t2 * 8 + 7]);
      *(u32x4*)(VT + d_ * 128 + ((j0 * 2) ^ ((d_ & 7) << 4))) = p;
    }
  };

  // ---- Q fragments (B-operand of swapped QK)
  bf16x8 qf[8];
  {
    const float* qr = q + ((size_t)b * N_SEQ + irow) * DM + hd * DH + h * 8;
    #pragma unroll
    for (int s = 0; s < 8; ++s) {
      float4 a = *(const float4*)(qr + s * 16);
      float4 c = *(const float4*)(qr + s * 16 + 4);
      u32x4 t4;
      t4[0] = pk2(a.x * scale, a.y * scale);
      t4[1] = pk2(a.z * scale, a.w * scale);
      t4[2] = pk2(c.x * scale, c.y * scale);
      t4[3] = pk2(c.z * scale, c.w * scale);
      qf[s] = __builtin_bit_cast(bf16x8, t4);
    }
  }

  float m_ = -INFINITY, ll = 0.f;
  f32x16 o[4];
  #pragma unroll
  for (int dt = 0; dt < 4; ++dt)
    #pragma unroll
    for (int r = 0; r < 16; ++r) o[dt][r] = 0.f;

  const int kswz = (il & 7) << 4;

  const int nt = 2 * qt + 2;

  // ---- prologue: stage tile 0
  issue_loads(0);
  write_lds(0);
  __syncthreads();

  int cur = 0;
  for (int t = 0; t < nt; ++t) {
    const int jt = t * KVB;
    const bool have_next = (t + 1 < nt);
    if (have_next) issue_loads(jt + KVB);     // in flight during compute

    if (jt <= wq0 + 31) {
      char* K  = ldsK  + cur * 16384;
      char* VT = ldsVT + cur * 16384;
      const bool act1 = (jt + 32 <= wq0 + 31);

      // ---- S^T = K Q^T
      f32x16 sc0 = {0,0,0,0,0,0,0,0,0,0,0,0,0,0,0,0};
      f32x16 sc1 = {0,0,0,0,0,0,0,0,0,0,0,0,0,0,0,0};
      __builtin_amdgcn_s_setprio(1);
      #pragma unroll
      for (int s = 0; s < 8; ++s) {
        bf16x8 kf0 = *(const bf16x8*)(K + il * 256 + ((s * 32 + h * 16) ^ kswz));
        sc0 = __builtin_amdgcn_mfma_f32_32x32x16_bf16(kf0, qf[s], sc0, 0, 0, 0);
      }
      if (act1) {
        #pragma unroll
        for (int s = 0; s < 8; ++s) {
          bf16x8 kf1 = *(const bf16x8*)(K + (32 + il) * 256 + ((s * 32 + h * 16) ^ kswz));
          sc1 = __builtin_amdgcn_mfma_f32_32x32x16_bf16(kf1, qf[s], sc1, 0, 0, 0);
        }
      }
      __builtin_amdgcn_s_setprio(0);

      // ---- causal mask
      if (jt + 31 > wq0) {
        #pragma unroll
        for (int r = 0; r < 16; ++r) {
          int j = jt + (r & 3) + 8 * (r >> 2) + 4 * h;
          sc0[r] = (j > irow) ? MASK_VAL : sc0[r];
        }
      }
      if (act1 && (jt + 63 > wq0)) {
        #pragma unroll
        for (int r = 0; r < 16; ++r) {
          int j = jt + 32 + (r & 3) + 8 * (r >> 2) + 4 * h;
          sc1[r] = (j > irow) ? MASK_VAL : sc1[r];
        }
      }

      // ---- online softmax, defer-max (T13)
      float pmax = sc0[0];
      #pragma unroll
      for (int r = 1; r < 16; ++r) pmax = fmaxf(pmax, sc0[r]);
      if (act1) {
        #pragma unroll
        for (int r = 0; r < 16; ++r) pmax = fmaxf(pmax, sc1[r]);
      }
      pmax = fmaxf(pmax, __shfl_xor(pmax, 32));

      if (!__all(pmax <= m_ + 8.f)) {
        const float mnew = fmaxf(m_, pmax);
        const float alpha = __expf(m_ - mnew);
        ll *= alpha;
        m_ = mnew;
        ldsA[w * 32 + il] = alpha;
        f32x4 av[4];
        #pragma unroll
        for (int m = 0; m < 4; ++m)
          av[m] = *(const f32x4*)(ldsA + w * 32 + 8 * m + 4 * h);
        #pragma unroll
        for (int dt = 0; dt < 4; ++dt)
          #pragma unroll
          for (int m = 0; m < 4; ++m)
            #pragma unroll
            for (int r2 = 0; r2 < 4; ++r2)
              o[dt][m * 4 + r2] *= av[m][r2];
      }

      #pragma unroll
      for (int r = 0; r < 16; ++r) sc0[r] = __expf(sc0[r] - m_);
      if (act1) {
        #pragma unroll
        for (int r = 0; r < 16; ++r) sc1[r] = __expf(sc1[r] - m_);
      }
      float rs = 0.f;
      #pragma unroll
      for (int r = 0; r < 16; ++r) rs += sc0[r];
      if (act1) {
        #pragma unroll
        for (int r = 0; r < 16; ++r) rs += sc1[r];
      }
      rs += __shfl_xor(rs, 32);
      ll += rs;

      // ---- pack P -> bf16 A-fragments (T12)
      bf16x8 pa0[2], pa1[2];
      #pragma unroll
      for (int ss = 0; ss < 2; ++ss) {
        u32 w0 = pk2(sc0[8 * ss + 0], sc0[8 * ss + 1]);
        u32 w1 = pk2(sc0[8 * ss + 2], sc0[8 * ss + 3]);
        u32 w2 = pk2(sc0[8 * ss + 4], sc0[8 * ss + 5]);
        u32 w3 = pk2(sc0[8 * ss + 6], sc0[8 * ss + 7]);
        asm volatile("v_permlane32_swap_b32 %0, %1" : "+v"(w0), "+v"(w2));
        asm volatile("v_permlane32_swap_b32 %0, %1" : "+v"(w1), "+v"(w3));
        u32x4 t4 = {w0, w1, w2, w3};
        pa0[ss] = __builtin_bit_cast(bf16x8, t4);
      }
      if (act1) {
        #pragma unroll
        for (int ss = 0; ss < 2; ++ss) {
          u32 w0 = pk2(sc1[8 * ss + 0], sc1[8 * ss + 1]);
          u32 w1 = pk2(sc1[8 * ss + 2], sc1[8 * ss + 3]);
          u32 w2 = pk2(sc1[8 * ss + 4], sc1[8 * ss + 5]);
          u32 w3 = pk2(sc1[8 * ss + 6], sc1[8 * ss + 7]);
          asm volatile("v_permlane32_swap_b32 %0, %1" : "+v"(w0), "+v"(w2));
          asm volatile("v_permlane32_swap_b32 %0, %1" : "+v"(w1), "+v"(w3));
          u32x4 t4 = {w0, w1, w2, w3};
          pa1[ss] = __builtin_bit_cast(bf16x8, t4);
        }
      }

      // ---- O += P V
      __builtin_amdgcn_s_setprio(1);
      #pragma unroll
      for (int dt = 0; dt < 4; ++dt) {
        const int drow = dt * 32 + il;
        char* vrow = VT + drow * 128;
        bf16x8 vf0 = *(const bf16x8*)(vrow + ((0 * 32 + 16 * h) ^ kswz));
        o[dt] = __builtin_amdgcn_mfma_f32_32x32x16_bf16(pa0[0], vf0, o[dt], 0, 0, 0);
        bf16x8 vf1 = *(const bf16x8*)(vrow + ((1 * 32 + 16 * h) ^ kswz));
        o[dt] = __builtin_amdgcn_mfma_f32_32x32x16_bf16(pa0[1], vf1, o[dt], 0, 0, 0);
        if (act1) {
          bf16x8 vf2 = *(const bf16x8*)(vrow + ((2 * 32 + 16 * h) ^ kswz));
          o[dt] = __builtin_amdgcn_mfma_f32_32x32x16_bf16(pa1[0], vf2, o[dt], 0, 0, 0);
          bf16x8 vf3 = *(const bf16x8*)(vrow + ((3 * 32 + 16 * h) ^ kswz));
          o[dt] = __builtin_amdgcn_mfma_f32_32x32x16_bf16(pa1[1], vf3, o[dt], 0, 0, 0);
        }
      }
      __builtin_amdgcn_s_setprio(0);
    }

    if (have_next) {
      write_lds(cur ^ 1);     // waits vmcnt on kr/vr, writes other buffer
      __syncthreads();
      cur ^= 1;
    }
  }

  // ---- epilogue
  ldsA[w * 32 + il] = 1.0f / ll;
  f32x4 iv[4];
  #pragma unroll
  for (int m = 0; m < 4; ++m)
    iv[m] = *(const f32x4*)(ldsA + w * 32 + 8 * m + 4 * h);

  float* ob = out + ((size_t)b * N_SEQ + wq0) * DM + hd * DH;
  #pragma unroll
  for (int dt = 0; dt < 4; ++dt) {
    #pragma unroll
    for (int m = 0; m < 4; ++m) {
      #pragma unroll
      for (int r2 = 0; r2 < 4; ++r2) {
        int i_loc = 8 * m + 4 * h + r2;
        ob[(size_t)i_loc * DM + dt * 32 + il] = o[dt][m * 4 + r2] * iv[m][r2];
      }
    }
  }
}

extern "C" void kernel_launch(void* const* d_in, const int* in_sizes, int n_in,
                              void* d_out, int out_size, void* d_ws, size_t ws_size,
                              hipStream_t stream) {
  const float* q = (const float*)d_in[0];
  const float* k = (const float*)d_in[1];
  const float* v = (const float*)d_in[2];
  float* out = (float*)d_out;
  dim3 grid(B_SZ * NH * NQT);   // 512 blocks, 2/CU, paired qt for balance
  attn_fwd<<<grid, 256, 0, stream>>>(q, k, v, out);
}

// Round 6
// 90.563 us; speedup vs baseline: 4.2743x; 4.2743x over previous
//
#include <hip/hip_runtime.h>
#include <hip/hip_bf16.h>

#define B_SZ   2
#define N_SEQ  2048
#define NH     16
#define DH     128
#define DM     2048
#define QB     128               // 4 warps x 32 q-rows
#define KVB    64
#define NQT    (N_SEQ / QB)      // 16
#define MASK_VAL (-50000.0f)

typedef short bf16x8 __attribute__((ext_vector_type(8)));
typedef float f32x4  __attribute__((ext_vector_type(4)));
typedef float f32x16 __attribute__((ext_vector_type(16)));
typedef unsigned u32;
typedef unsigned u32x2 __attribute__((ext_vector_type(2)));
typedef unsigned u32x4 __attribute__((ext_vector_type(4)));
typedef unsigned short ushort_t;

__device__ __forceinline__ u32 pk2(float a, float b) {
  u32 r;
  asm("v_cvt_pk_bf16_f32 %0, %1, %2" : "=v"(r) : "v"(a), "v"(b));
  return r;
}

__device__ __forceinline__ void gload_lds16(const void* g, void* l) {
  __builtin_amdgcn_global_load_lds(
      (const __attribute__((address_space(1))) unsigned int*)g,
      (__attribute__((address_space(3))) unsigned int*)l, 16, 0, 0);
}

// ---------- prepass A: K fp32 [b][n][h*128+d] -> bf16 [b][h][n][d] ----------
__global__ __launch_bounds__(256)
void kconv(const float* __restrict__ k, ushort_t* __restrict__ kw) {
  const int idx = blockIdx.x * 256 + threadIdx.x;
  const size_t e0 = (size_t)idx * 16;
  const int c0 = (int)(e0 & 2047);
  const int bn = (int)(e0 >> 11);           // b*2048 + n
  const int b  = bn >> 11;
  const int n  = bn & 2047;
  const int h  = c0 >> 7;
  const int d0 = c0 & 127;
  const float* src = k + e0;
  float4 f0 = *(const float4*)(src);
  float4 f1 = *(const float4*)(src + 4);
  float4 f2 = *(const float4*)(src + 8);
  float4 f3 = *(const float4*)(src + 12);
  u32x4 p0, p1;
  p0[0] = pk2(f0.x, f0.y); p0[1] = pk2(f0.z, f0.w);
  p0[2] = pk2(f1.x, f1.y); p0[3] = pk2(f1.z, f1.w);
  p1[0] = pk2(f2.x, f2.y); p1[1] = pk2(f2.z, f2.w);
  p1[2] = pk2(f3.x, f3.y); p1[3] = pk2(f3.z, f3.w);
  ushort_t* dst = kw + (((size_t)(b * 16 + h) * 2048 + n) * 128 + d0);
  *(u32x4*)(dst)     = p0;
  *(u32x4*)(dst + 8) = p1;
}

// ---------- prepass B: V fp32 [b][n][h*128+d] -> bf16 VT [b][h][d][n] ----------
__global__ __launch_bounds__(256)
void vtrans(const float* __restrict__ v, ushort_t* __restrict__ vw) {
  __shared__ __align__(16) char tile[16384];   // [64 n][128 d] bf16, XOR-swizzled

  const int tid   = threadIdx.x;
  const int bid   = blockIdx.x;
  const int ntile = bid & 31;
  const int bh2   = bid >> 5;           // b*16 + h
  const int h     = bh2 & 15;
  const int n0    = ntile * 64;
  const float* vbase = v + (size_t)(bh2 >> 4) * N_SEQ * DM + h * DH;

  // read phase: 64 rows x 128 d, store bf16 to LDS [n][d] swizzled
  #pragma unroll
  for (int i = 0; i < 8; ++i) {
    int idx = i * 256 + tid;            // 0..2047
    int n   = idx >> 5;                 // 0..63
    int c4  = idx & 31;                 // d0 = 4*c4
    float4 f = *(const float4*)(vbase + (size_t)(n0 + n) * DM + c4 * 4);
    u32x2 p;
    p[0] = pk2(f.x, f.y);
    p[1] = pk2(f.z, f.w);
    int sw = (((n & 7) ^ (n >> 3)) << 4);
    *(u32x2*)(tile + n * 256 + ((8 * c4) ^ sw)) = p;
  }
  __syncthreads();

  // write phase: per thread one 16B block = 8 n's for fixed d
  #pragma unroll
  for (int i = 0; i < 4; ++i) {
    int idx = i * 256 + tid;            // 0..1023
    int d   = idx >> 3;                 // 0..127
    int nb  = idx & 7;
    u32x4 p;
    #pragma unroll
    for (int half = 0; half < 4; ++half) {
      int na = nb * 8 + half * 2;
      int nA = na, nB = na + 1;
      int swA = (((nA & 7) ^ (nA >> 3)) << 4);
      int swB = (((nB & 7) ^ (nB >> 3)) << 4);
      u32 lo = *(const ushort_t*)(tile + nA * 256 + (((d >> 2) * 8) ^ swA) + (d & 3) * 2);
      u32 hi = *(const ushort_t*)(tile + nB * 256 + (((d >> 2) * 8) ^ swB) + (d & 3) * 2);
      p[half] = lo | (hi << 16);
    }
    ushort_t* dst = vw + (((size_t)bh2 * 128 + d) * 2048 + n0 + nb * 8);
    *(u32x4*)(dst) = p;
  }
}

// ---------- main attention kernel ----------
__global__ __launch_bounds__(256, 2)
void attn_fwd(const float* __restrict__ q, const ushort_t* __restrict__ kw,
              const ushort_t* __restrict__ vw, float* __restrict__ out) {
  __shared__ __align__(16) char  ldsK[64 * 256];     // K[64][128] bf16, XOR-swizzled
  __shared__ __align__(16) char  ldsVT[128 * 128];   // VT[128 d][64 j] bf16, swizzled
  __shared__ __align__(16) float ldsA[4 * 32];       // per-warp alpha/inv broadcast

  const int tid  = threadIdx.x;
  const int lane = tid & 63;
  const int w    = tid >> 6;
  const int h    = lane >> 5;     // wave half
  const int il   = lane & 31;

  const int bid = blockIdx.x;
  const int bh  = bid & 31;
  const int qt  = (bid < 256) ? (bid >> 5) : (NQT - 1 - ((bid - 256) >> 5));
  const int b   = bh >> 4;
  const int hd  = bh & 15;
  const int q0  = qt * QB;
  const int wq0 = q0 + w * 32;
  const int irow = wq0 + il;

  const float scale = 0.08838834764831845f;  // 128^-0.5

  const ushort_t* kb16 = kw + (size_t)(b * 16 + hd) * N_SEQ * DH;
  const ushort_t* vt16 = vw + (size_t)(b * 16 + hd) * DH * N_SEQ;

  // ---- Q fragments (B-operand of swapped QK)
  bf16x8 qf[8];
  {
    const float* qr = q + ((size_t)b * N_SEQ + irow) * DM + hd * DH + h * 8;
    #pragma unroll
    for (int s = 0; s < 8; ++s) {
      float4 a = *(const float4*)(qr + s * 16);
      float4 c = *(const float4*)(qr + s * 16 + 4);
      u32x4 t4;
      t4[0] = pk2(a.x * scale, a.y * scale);
      t4[1] = pk2(a.z * scale, a.w * scale);
      t4[2] = pk2(c.x * scale, c.y * scale);
      t4[3] = pk2(c.z * scale, c.w * scale);
      qf[s] = __builtin_bit_cast(bf16x8, t4);
    }
  }

  float m_ = -INFINITY, ll = 0.f;
  f32x16 o[4];
  #pragma unroll
  for (int dt = 0; dt < 4; ++dt)
    #pragma unroll
    for (int r = 0; r < 16; ++r) o[dt][r] = 0.f;

  const int kswz = (il & 7) << 4;
  const int nt = 2 * qt + 2;

  // staging lane constants
  const int krL = lane >> 4;        // row-within-1KB for K (4 rows/call)
  const int kpL = lane & 15;        // 16B block in K row
  const int vdL = lane >> 3;        // d-within-1KB for VT (8 rows/call)
  const int vcL = lane & 7;         // 16B block in VT row

  for (int t = 0; t < nt; ++t) {
    const int jt = t * KVB;
    if (t) __syncthreads();    // everyone done reading previous tile

    // ---- stage K tile: 4 x global_load_lds(16B) per wave, pre-swizzled source
    {
      const ushort_t* kt = kb16 + (size_t)jt * DH;
      #pragma unroll
      for (int c = 0; c < 4; ++c) {
        const int base = (w * 4 + c) * 1024;
        const int r    = (w * 4 + c) * 4 + krL;          // 0..63
        const ushort_t* g = kt + (size_t)r * DH + ((kpL ^ (r & 7)) * 8);
        gload_lds16(g, ldsK + base);
      }
      // ---- stage VT tile
      #pragma unroll
      for (int c = 0; c < 4; ++c) {
        const int base = (w * 4 + c) * 1024;
        const int d    = (w * 4 + c) * 8 + vdL;          // 0..127
        const ushort_t* g = vt16 + (size_t)d * N_SEQ + jt + ((vcL ^ (d & 7)) * 8);
        gload_lds16(g, ldsVT + base);
      }
    }
    __syncthreads();           // drains vmcnt (compiler emits before barrier)

    if (jt > wq0 + 31) continue;           // fully masked for this warp
    const bool act1 = (jt + 32 <= wq0 + 31);

    // ---- S^T = K Q^T
    f32x16 sc0 = {0,0,0,0,0,0,0,0,0,0,0,0,0,0,0,0};
    f32x16 sc1 = {0,0,0,0,0,0,0,0,0,0,0,0,0,0,0,0};
    __builtin_amdgcn_s_setprio(1);
    #pragma unroll
    for (int s = 0; s < 8; ++s) {
      bf16x8 kf0 = *(const bf16x8*)(ldsK + il * 256 + ((s * 32 + h * 16) ^ kswz));
      sc0 = __builtin_amdgcn_mfma_f32_32x32x16_bf16(kf0, qf[s], sc0, 0, 0, 0);
    }
    if (act1) {
      #pragma unroll
      for (int s = 0; s < 8; ++s) {
        bf16x8 kf1 = *(const bf16x8*)(ldsK + (32 + il) * 256 + ((s * 32 + h * 16) ^ kswz));
        sc1 = __builtin_amdgcn_mfma_f32_32x32x16_bf16(kf1, qf[s], sc1, 0, 0, 0);
      }
    }
    __builtin_amdgcn_s_setprio(0);

    // ---- causal mask
    if (jt + 31 > wq0) {
      #pragma unroll
      for (int r = 0; r < 16; ++r) {
        int j = jt + (r & 3) + 8 * (r >> 2) + 4 * h;
        sc0[r] = (j > irow) ? MASK_VAL : sc0[r];
      }
    }
    if (act1 && (jt + 63 > wq0)) {
      #pragma unroll
      for (int r = 0; r < 16; ++r) {
        int j = jt + 32 + (r & 3) + 8 * (r >> 2) + 4 * h;
        sc1[r] = (j > irow) ? MASK_VAL : sc1[r];
      }
    }

    // ---- online softmax, defer-max (T13)
    float pmax = sc0[0];
    #pragma unroll
    for (int r = 1; r < 16; ++r) pmax = fmaxf(pmax, sc0[r]);
    if (act1) {
      #pragma unroll
      for (int r = 0; r < 16; ++r) pmax = fmaxf(pmax, sc1[r]);
    }
    pmax = fmaxf(pmax, __shfl_xor(pmax, 32));

    if (!__all(pmax <= m_ + 8.f)) {
      const float mnew = fmaxf(m_, pmax);
      const float alpha = __expf(m_ - mnew);
      ll *= alpha;
      m_ = mnew;
      ldsA[w * 32 + il] = alpha;
      f32x4 av[4];
      #pragma unroll
      for (int m = 0; m < 4; ++m)
        av[m] = *(const f32x4*)(ldsA + w * 32 + 8 * m + 4 * h);
      #pragma unroll
      for (int dt = 0; dt < 4; ++dt)
        #pragma unroll
        for (int m = 0; m < 4; ++m)
          #pragma unroll
          for (int r2 = 0; r2 < 4; ++r2)
            o[dt][m * 4 + r2] *= av[m][r2];
    }

    #pragma unroll
    for (int r = 0; r < 16; ++r) sc0[r] = __expf(sc0[r] - m_);
    if (act1) {
      #pragma unroll
      for (int r = 0; r < 16; ++r) sc1[r] = __expf(sc1[r] - m_);
    }
    float rs = 0.f;
    #pragma unroll
    for (int r = 0; r < 16; ++r) rs += sc0[r];
    if (act1) {
      #pragma unroll
      for (int r = 0; r < 16; ++r) rs += sc1[r];
    }
    rs += __shfl_xor(rs, 32);
    ll += rs;

    // ---- pack P -> bf16 A-fragments (T12)
    bf16x8 pa0[2], pa1[2];
    #pragma unroll
    for (int ss = 0; ss < 2; ++ss) {
      u32 w0 = pk2(sc0[8 * ss + 0], sc0[8 * ss + 1]);
      u32 w1 = pk2(sc0[8 * ss + 2], sc0[8 * ss + 3]);
      u32 w2 = pk2(sc0[8 * ss + 4], sc0[8 * ss + 5]);
      u32 w3 = pk2(sc0[8 * ss + 6], sc0[8 * ss + 7]);
      asm volatile("v_permlane32_swap_b32 %0, %1" : "+v"(w0), "+v"(w2));
      asm volatile("v_permlane32_swap_b32 %0, %1" : "+v"(w1), "+v"(w3));
      u32x4 t4 = {w0, w1, w2, w3};
      pa0[ss] = __builtin_bit_cast(bf16x8, t4);
    }
    if (act1) {
      #pragma unroll
      for (int ss = 0; ss < 2; ++ss) {
        u32 w0 = pk2(sc1[8 * ss + 0], sc1[8 * ss + 1]);
        u32 w1 = pk2(sc1[8 * ss + 2], sc1[8 * ss + 3]);
        u32 w2 = pk2(sc1[8 * ss + 4], sc1[8 * ss + 5]);
        u32 w3 = pk2(sc1[8 * ss + 6], sc1[8 * ss + 7]);
        asm volatile("v_permlane32_swap_b32 %0, %1" : "+v"(w0), "+v"(w2));
        asm volatile("v_permlane32_swap_b32 %0, %1" : "+v"(w1), "+v"(w3));
        u32x4 t4 = {w0, w1, w2, w3};
        pa1[ss] = __builtin_bit_cast(bf16x8, t4);
      }
    }

    // ---- O += P V
    __builtin_amdgcn_s_setprio(1);
    #pragma unroll
    for (int dt = 0; dt < 4; ++dt) {
      const int drow = dt * 32 + il;
      char* vrow = ldsVT + drow * 128;
      bf16x8 vf0 = *(const bf16x8*)(vrow + ((0 * 32 + 16 * h) ^ kswz));
      o[dt] = __builtin_amdgcn_mfma_f32_32x32x16_bf16(pa0[0], vf0, o[dt], 0, 0, 0);
      bf16x8 vf1 = *(const bf16x8*)(vrow + ((1 * 32 + 16 * h) ^ kswz));
      o[dt] = __builtin_amdgcn_mfma_f32_32x32x16_bf16(pa0[1], vf1, o[dt], 0, 0, 0);
      if (act1) {
        bf16x8 vf2 = *(const bf16x8*)(vrow + ((2 * 32 + 16 * h) ^ kswz));
        o[dt] = __builtin_amdgcn_mfma_f32_32x32x16_bf16(pa1[0], vf2, o[dt], 0, 0, 0);
        bf16x8 vf3 = *(const bf16x8*)(vrow + ((3 * 32 + 16 * h) ^ kswz));
        o[dt] = __builtin_amdgcn_mfma_f32_32x32x16_bf16(pa1[1], vf3, o[dt], 0, 0, 0);
      }
    }
    __builtin_amdgcn_s_setprio(0);
  }

  // ---- epilogue
  ldsA[w * 32 + il] = 1.0f / ll;
  f32x4 iv[4];
  #pragma unroll
  for (int m = 0; m < 4; ++m)
    iv[m] = *(const f32x4*)(ldsA + w * 32 + 8 * m + 4 * h);

  float* ob = out + ((size_t)b * N_SEQ + wq0) * DM + hd * DH;
  #pragma unroll
  for (int dt = 0; dt < 4; ++dt) {
    #pragma unroll
    for (int m = 0; m < 4; ++m) {
      #pragma unroll
      for (int r2 = 0; r2 < 4; ++r2) {
        int i_loc = 8 * m + 4 * h + r2;
        ob[(size_t)i_loc * DM + dt * 32 + il] = o[dt][m * 4 + r2] * iv[m][r2];
      }
    }
  }
}

extern "C" void kernel_launch(void* const* d_in, const int* in_sizes, int n_in,
                              void* d_out, int out_size, void* d_ws, size_t ws_size,
                              hipStream_t stream) {
  const float* q = (const float*)d_in[0];
  const float* k = (const float*)d_in[1];
  const float* v = (const float*)d_in[2];
  float* out = (float*)d_out;

  ushort_t* kw = (ushort_t*)d_ws;                                // 16 MB
  ushort_t* vw = kw + (size_t)B_SZ * NH * N_SEQ * DH;            // 16 MB

  kconv <<<2048, 256, 0, stream>>>(k, kw);
  vtrans<<<1024, 256, 0, stream>>>(v, vw);
  attn_fwd<<<B_SZ * NH * NQT, 256, 0, stream>>>(q, kw, vw, out); // 512 blocks
}